// Round 6
// baseline (113.937 us; speedup 1.0000x reference)
//
#include <hip/hip_runtime.h>
#include <hip/hip_bf16.h>
#include <math.h>

#define LSEQ 1024
#define EDIM 512
#define HD 64
#define CCH 32
#define NCH 32
#define DFEAT 128

typedef unsigned short u16;
typedef short bf16x8 __attribute__((ext_vector_type(8)));
typedef float f32x4 __attribute__((ext_vector_type(4)));

__device__ __forceinline__ u16 f2bf(float f) {
    unsigned u = __float_as_uint(f);
    unsigned r = (u + 0x7fffu + ((u >> 16) & 1u)) >> 16;
    return (u16)r;
}
__device__ __forceinline__ float bf2f(u16 x) {
    return __uint_as_float((unsigned)x << 16);
}
__device__ __forceinline__ void cvt2(float a, float b, u16& x, u16& y) {
    float2 f; f.x = a; f.y = b;
    __hip_bfloat162 p = __float22bfloat162_rn(f);
    x = *reinterpret_cast<u16*>(&p.x);
    y = *reinterpret_cast<u16*>(&p.y);
}
__device__ __forceinline__ bf16x8 pack8(float4 a, float4 b) {
    u16 r[8];
    cvt2(a.x, a.y, r[0], r[1]); cvt2(a.z, a.w, r[2], r[3]);
    cvt2(b.x, b.y, r[4], r[5]); cvt2(b.z, b.w, r[6], r[7]);
    return *(bf16x8*)r;
}
__device__ __forceinline__ void async16(void* lds, const void* g) {
    __builtin_amdgcn_global_load_lds(
        (const __attribute__((address_space(1))) unsigned int*)g,
        (__attribute__((address_space(3))) unsigned int*)lds, 16, 0, 0);
}

// ---------------- fused: QKV projection (fp32 in, bf16 MFMA) + feature map
//                 + per-chunk KV outer-product sums + K1 sums
// block = (chunk tile, head): 64 rows (32 l x 2 b) x 64 cols of Wq/Wk/Wv
__global__ __launch_bounds__(256) void qkvchunk_kernel(
    const float* __restrict__ X,
    const float* __restrict__ Wq, const float* __restrict__ bq,
    const float* __restrict__ Wk, const float* __restrict__ bk,
    const float* __restrict__ Wv, const float* __restrict__ bv,
    u16* __restrict__ qf, u16* __restrict__ kf, u16* __restrict__ vf,
    u16* __restrict__ KVc, float* __restrict__ K1c)
{
    __shared__ union {
        struct { u16 As[64 * 32], Bq[64 * 32], Bk[64 * 32], Bv[64 * 32]; } p1; // 16 KB
        struct { u16 KT[2 * 128 * 32], VT[2 * 64 * 32]; } p2;                   // 24 KB
    } sh;
    const int bx = blockIdx.x;
    const int tile = bx >> 3, h = bx & 7;     // tile = chunk index c
    const int r0 = tile * 64, j0 = h * 64;
    const int t = threadIdx.x;
    const int wave = t >> 6, lane = t & 63;
    const int cl = lane & 15, rg4 = lane >> 4;
    const int rpair = wave >> 1, half = wave & 1;

    const int srow = t >> 2, sq4 = (t & 3) * 8;   // staging: row 0..63, col group

    f32x4 accq[2][2], acck[2][2], accv[2][2];
    #pragma unroll
    for (int ri = 0; ri < 2; ++ri)
        #pragma unroll
        for (int cjl = 0; cjl < 2; ++cjl) {
            accq[ri][cjl] = (f32x4){0.f, 0.f, 0.f, 0.f};
            acck[ri][cjl] = (f32x4){0.f, 0.f, 0.f, 0.f};
            accv[ri][cjl] = (f32x4){0.f, 0.f, 0.f, 0.f};
        }

    // prefetch kb=0 tiles into registers (fp32)
    const float* xrp = X  + (size_t)(r0 + srow) * 512 + sq4;
    const float* qrp = Wq + (size_t)(j0 + srow) * 512 + sq4;
    const float* krp = Wk + (size_t)(j0 + srow) * 512 + sq4;
    const float* vrp = Wv + (size_t)(j0 + srow) * 512 + sq4;
    float4 xr0 = *(const float4*)xrp,       xr1 = *(const float4*)(xrp + 4);
    float4 wq0 = *(const float4*)qrp,       wq1 = *(const float4*)(qrp + 4);
    float4 wk0 = *(const float4*)krp,       wk1 = *(const float4*)(krp + 4);
    float4 wv0 = *(const float4*)vrp,       wv1 = *(const float4*)(vrp + 4);

    for (int kb = 0; kb < 512; kb += 32) {
        __syncthreads();
        *(bf16x8*)&sh.p1.As[srow * 32 + sq4] = pack8(xr0, xr1);
        *(bf16x8*)&sh.p1.Bq[srow * 32 + sq4] = pack8(wq0, wq1);
        *(bf16x8*)&sh.p1.Bk[srow * 32 + sq4] = pack8(wk0, wk1);
        *(bf16x8*)&sh.p1.Bv[srow * 32 + sq4] = pack8(wv0, wv1);
        __syncthreads();
        if (kb + 32 < 512) {
            const float* xp = xrp + kb + 32;
            const float* qp = qrp + kb + 32;
            const float* kp = krp + kb + 32;
            const float* vp = vrp + kb + 32;
            xr0 = *(const float4*)xp; xr1 = *(const float4*)(xp + 4);
            wq0 = *(const float4*)qp; wq1 = *(const float4*)(qp + 4);
            wk0 = *(const float4*)kp; wk1 = *(const float4*)(kp + 4);
            wv0 = *(const float4*)vp; wv1 = *(const float4*)(vp + 4);
        }
        bf16x8 af[2];
        #pragma unroll
        for (int ri = 0; ri < 2; ++ri)
            af[ri] = *(const bf16x8*)&sh.p1.As[(rpair * 32 + ri * 16 + cl) * 32 + rg4 * 8];
        #pragma unroll
        for (int cjl = 0; cjl < 2; ++cjl) {
            const int cj = half * 2 + cjl;
            bf16x8 b1 = *(const bf16x8*)&sh.p1.Bq[(cj * 16 + cl) * 32 + rg4 * 8];
            bf16x8 b2 = *(const bf16x8*)&sh.p1.Bk[(cj * 16 + cl) * 32 + rg4 * 8];
            bf16x8 b3 = *(const bf16x8*)&sh.p1.Bv[(cj * 16 + cl) * 32 + rg4 * 8];
            #pragma unroll
            for (int ri = 0; ri < 2; ++ri) {
                accq[ri][cjl] = __builtin_amdgcn_mfma_f32_16x16x32_bf16(af[ri], b1, accq[ri][cjl], 0, 0, 0);
                acck[ri][cjl] = __builtin_amdgcn_mfma_f32_16x16x32_bf16(af[ri], b2, acck[ri][cjl], 0, 0, 0);
                accv[ri][cjl] = __builtin_amdgcn_mfma_f32_16x16x32_bf16(af[ri], b3, accv[ri][cjl], 0, 0, 0);
            }
        }
    }
    __syncthreads();   // done with p1 before aliasing p2

    // epilogue: bias, relu, feature map; write qf/kf/vf + stage KT/VT in LDS
    float bqv[2], bkv[2], bvv[2];
    #pragma unroll
    for (int cjl = 0; cjl < 2; ++cjl) {
        const int jg = j0 + (half * 2 + cjl) * 16 + cl;
        bqv[cjl] = bq[jg]; bkv[cjl] = bk[jg]; bvv[cjl] = bv[jg];
    }
    #pragma unroll
    for (int ri = 0; ri < 2; ++ri) {
        #pragma unroll
        for (int rr = 0; rr < 4; ++rr) {
            const int row_loc = rpair * 32 + ri * 16 + rg4 * 4 + rr;
            const int row_g = r0 + row_loc;
            const int l = row_g >> 1, bb = row_loc & 1, lc = row_loc >> 1;
            const int n = bb * 8 + h;
            float ang = 1.5707963267948966f * (float)(l + 1) * (1.0f / 1024.0f);
            float sv, cv;
            sincosf(ang, &sv, &cv);
            const size_t qkbase = (size_t)(n * LSEQ + l) * DFEAT;
            const size_t vbase  = (size_t)(n * LSEQ + l) * HD;
            #pragma unroll
            for (int cjl = 0; cjl < 2; ++cjl) {
                const int d = (half * 2 + cjl) * 16 + cl;
                float yq = fmaxf(accq[ri][cjl][rr] + bqv[cjl], 0.f);
                u16 q0, q1; cvt2(yq * sv, yq * cv, q0, q1);
                qf[qkbase + d] = q0; qf[qkbase + d + 64] = q1;
                float yk = fmaxf(acck[ri][cjl][rr] + bkv[cjl], 0.f);
                u16 k0, k1; cvt2(yk * sv, yk * cv, k0, k1);
                kf[qkbase + d] = k0; kf[qkbase + d + 64] = k1;
                sh.p2.KT[(bb * 128 + d) * 32 + lc]      = k0;
                sh.p2.KT[(bb * 128 + d + 64) * 32 + lc] = k1;
                float yv = accv[ri][cjl][rr] + bvv[cjl];
                u16 v0 = f2bf(yv);
                vf[vbase + d] = v0;
                sh.p2.VT[(bb * 64 + d) * 32 + lc] = v0;
            }
        }
    }
    __syncthreads();

    // chunk phase: KV[m][d] = sum_l V[l][m] * K[l][d] for both bb; K1[d] = sum_l K[l][d]
    #pragma unroll
    for (int bb2 = 0; bb2 < 2; ++bb2) {
        bf16x8 af2 = *(const bf16x8*)&sh.p2.VT[(bb2 * 64 + wave * 16 + cl) * 32 + rg4 * 8];
        const int n2 = bb2 * 8 + h;
        u16* kvout = KVc + (size_t)(n2 * NCH + tile) * (HD * DFEAT);
        #pragma unroll
        for (int dt = 0; dt < 8; ++dt) {
            bf16x8 bf2 = *(const bf16x8*)&sh.p2.KT[(bb2 * 128 + dt * 16 + cl) * 32 + rg4 * 8];
            f32x4 a2 = __builtin_amdgcn_mfma_f32_16x16x32_bf16(af2, bf2, (f32x4){0.f,0.f,0.f,0.f}, 0, 0, 0);
            #pragma unroll
            for (int rr = 0; rr < 4; ++rr)
                kvout[(size_t)(wave * 16 + rg4 * 4 + rr) * 128 + dt * 16 + cl] = f2bf(a2[rr]);
        }
    }
    {
        const int bbk = t >> 7, dk = t & 127;
        float s = 0.f;
        #pragma unroll
        for (int g = 0; g < 4; ++g) {
            bf16x8 kv = *(const bf16x8*)&sh.p2.KT[(bbk * 128 + dk) * 32 + g * 8];
            #pragma unroll
            for (int j = 0; j < 8; ++j) s += bf2f(((u16*)&kv)[j]);
        }
        K1c[(size_t)((bbk * 8 + h) * NCH + tile) * DFEAT + dk] = s;
    }
}

// ---------------- exclusive prefix over chunks (bf16 KVc -> bf16 Spt; K1 -> fp32)
__global__ __launch_bounds__(256) void prefix_kernel(
    const u16* __restrict__ KVc, const float* __restrict__ K1c,
    u16* __restrict__ Spt, float* __restrict__ K1p)
{
    const int b = blockIdx.x, t = threadIdx.x;
    const int n = b >> 5;
    const int e = (b & 31) * 256 + t;   // 0..8191 (m*128+d)
    const u16* src = KVc + (size_t)n * NCH * 8192 + e;
    u16* dst = Spt + (size_t)n * NCH * 8192 + e;
    float v[32];
    #pragma unroll
    for (int cc = 0; cc < 32; ++cc) v[cc] = bf2f(src[(size_t)cc * 8192]);
    float run = 0.f;
    #pragma unroll
    for (int cc = 0; cc < 32; ++cc) { dst[(size_t)cc * 8192] = f2bf(run); run += v[cc]; }
    if (b < 8) {
        const int idx = b * 256 + t;  // 0..2047
        const int nn = idx >> 7, d = idx & 127;
        const float* s2 = K1c + (size_t)nn * NCH * DFEAT + d;
        float* d2 = K1p + (size_t)nn * NCH * DFEAT + d;
        float v2[32];
        #pragma unroll
        for (int cc = 0; cc < 32; ++cc) v2[cc] = s2[cc * DFEAT];
        float run2 = 0.f;
        #pragma unroll
        for (int cc = 0; cc < 32; ++cc) { d2[cc * DFEAT] = run2; run2 += v2[cc]; }
    }
}

// ---------------- intra-chunk attention via MFMA + prefix terms + normalize
__global__ __launch_bounds__(256) void attn_kernel(
    const u16* __restrict__ qf, const u16* __restrict__ kf, const u16* __restrict__ vf,
    const u16* __restrict__ Spt, const float* __restrict__ K1p,
    u16* __restrict__ Amb)
{
    const int n = blockIdx.x >> 5;
    const int c = blockIdx.x & 31;
    __shared__ u16 Qs[32 * 136];   // padded rows
    __shared__ u16 Ks[32 * 136];
    __shared__ u16 VT[64 * 32];    // [m][l]
    __shared__ u16 Am[32 * 32];    // masked A, bf16, l-major
    __shared__ float K1s[128];
    __shared__ float dsum2[2][32];
    __shared__ float qk1[32];
    const int t = threadIdx.x;
    const int wave = t >> 6, lane = t & 63;
    const int cl = lane & 15, rg4 = lane >> 4;
    const int mi = wave >> 1, nh = wave & 1;

    const u16* qbase = qf + (size_t)(n * LSEQ + c * CCH) * DFEAT;
    const u16* kbase = kf + (size_t)(n * LSEQ + c * CCH) * DFEAT;
    const u16* vbase = vf + (size_t)(n * LSEQ + c * CCH) * HD;
    const u16* spbase = Spt + (size_t)(n * NCH + c) * 8192;

    // prefetch S_prev B-frags straight from global (16B per lane)
    bf16x8 spf[2][4];
    #pragma unroll
    for (int ni2 = 0; ni2 < 2; ++ni2)
        #pragma unroll
        for (int ks = 0; ks < 4; ++ks)
            spf[ni2][ks] = *(const bf16x8*)&spbase[((2 * nh + ni2) * 16 + cl) * 128 + ks * 32 + rg4 * 8];

    // stage Q,K into padded LDS
    #pragma unroll
    for (int i = 0; i < 2; ++i) {
        int chunk = i * 256 + t;            // 0..511
        int row = chunk >> 4, c8 = chunk & 15;
        *(bf16x8*)&Qs[row * 136 + c8 * 8] = *(const bf16x8*)&qbase[row * 128 + c8 * 8];
        *(bf16x8*)&Ks[row * 136 + c8 * 8] = *(const bf16x8*)&kbase[row * 128 + c8 * 8];
    }
    {   // V transpose (coalesced scalar reads)
        u16 tmp[8];
        #pragma unroll
        for (int j = 0; j < 8; ++j) tmp[j] = vbase[(wave * 8 + j) * HD + lane];
        *(bf16x8*)&VT[lane * 32 + wave * 8] = *(bf16x8*)tmp;
    }
    if (t < 128) K1s[t] = K1p[(size_t)(n * NCH + c) * DFEAT + t];
    __syncthreads();

    // QK^T tile (mi, nh)
    f32x4 a_acc = (f32x4){0.f, 0.f, 0.f, 0.f};
    #pragma unroll
    for (int ks = 0; ks < 4; ++ks) {
        bf16x8 aq = *(const bf16x8*)&Qs[(mi * 16 + cl) * 136 + ks * 32 + rg4 * 8];
        bf16x8 bk = *(const bf16x8*)&Ks[(nh * 16 + cl) * 136 + ks * 32 + rg4 * 8];
        a_acc = __builtin_amdgcn_mfma_f32_16x16x32_bf16(aq, bk, a_acc, 0, 0, 0);
    }
    // mask, fp32 rowsum, write bf16 A
    #pragma unroll
    for (int r = 0; r < 4; ++r) {
        int l_loc = mi * 16 + rg4 * 4 + r;
        int lp_loc = nh * 16 + cl;
        float v = (lp_loc <= l_loc) ? a_acc[r] : 0.f;
        Am[l_loc * 32 + lp_loc] = f2bf(v);
        float s = v;
        s += __shfl_xor(s, 1); s += __shfl_xor(s, 2);
        s += __shfl_xor(s, 4); s += __shfl_xor(s, 8);
        if (cl == 0) dsum2[nh][l_loc] = s;
    }
    {   // q . K1_prev per row: 8 lanes per row, 16 d each
        int row = wave * 8 + (lane >> 3), seg = lane & 7;
        float s = 0.f;
        #pragma unroll
        for (int j = 0; j < 16; ++j) {
            int d = seg * 16 + j;
            s += bf2f(Qs[row * 136 + d]) * K1s[d];
        }
        s += __shfl_xor(s, 1); s += __shfl_xor(s, 2); s += __shfl_xor(s, 4);
        if (seg == 0) qk1[row] = s;
    }
    __syncthreads();

    // C = Q @ S_prev + A_masked @ V
    f32x4 oacc[2] = {(f32x4){0.f,0.f,0.f,0.f}, (f32x4){0.f,0.f,0.f,0.f}};
    #pragma unroll
    for (int ks = 0; ks < 4; ++ks) {
        bf16x8 aq = *(const bf16x8*)&Qs[(mi * 16 + cl) * 136 + ks * 32 + rg4 * 8];
        #pragma unroll
        for (int ni2 = 0; ni2 < 2; ++ni2)
            oacc[ni2] = __builtin_amdgcn_mfma_f32_16x16x32_bf16(aq, spf[ni2][ks], oacc[ni2], 0, 0, 0);
    }
    {
        bf16x8 aa = *(const bf16x8*)&Am[(mi * 16 + cl) * 32 + rg4 * 8];
        #pragma unroll
        for (int ni2 = 0; ni2 < 2; ++ni2) {
            bf16x8 bv = *(const bf16x8*)&VT[((2 * nh + ni2) * 16 + cl) * 32 + rg4 * 8];
            oacc[ni2] = __builtin_amdgcn_mfma_f32_16x16x32_bf16(aa, bv, oacc[ni2], 0, 0, 0);
        }
    }
    // normalize + scatter to Amb
    const int bb = n >> 3, h = n & 7;
    #pragma unroll
    for (int r = 0; r < 4; ++r) {
        int l_loc = mi * 16 + rg4 * 4 + r;
        float den = fmaxf(dsum2[0][l_loc] + dsum2[1][l_loc] + qk1[l_loc], 1e-6f);
        float inv = 1.0f / den;
        int rrow = (c * CCH + l_loc) * 2 + bb;
        #pragma unroll
        for (int ni2 = 0; ni2 < 2; ++ni2) {
            int m = (2 * nh + ni2) * 16 + cl;
            Amb[(size_t)rrow * EDIM + h * 64 + m] = f2bf(oacc[ni2][r] * inv);
        }
    }
}

// ---------------- output projection via bf16 MFMA (64x64 tiles); Wo staged fp32->bf16
__global__ __launch_bounds__(256) void out_mfma_kernel(
    const u16* __restrict__ Amb, const float* __restrict__ Wo,
    const float* __restrict__ bo, float* __restrict__ out)
{
    const int r0 = blockIdx.x * 64;
    const int j0 = blockIdx.y * 64;
    __shared__ u16 As[64 * 32];
    __shared__ u16 Bs[64 * 32];
    const int t = threadIdx.x;
    const int wave = t >> 6, lane = t & 63;
    const int cl = lane & 15, rg4 = lane >> 4;
    const int srow = t >> 2, sq4 = (t & 3) * 8;
    f32x4 acc[4];
    #pragma unroll
    for (int cj = 0; cj < 4; ++cj) acc[cj] = (f32x4){0.f, 0.f, 0.f, 0.f};

    const float* wop = Wo + (size_t)(j0 + srow) * 512 + sq4;
    float4 w0 = *(const float4*)wop, w1 = *(const float4*)(wop + 4);

    for (int kb = 0; kb < 512; kb += 32) {
        __syncthreads();
        async16(&As[(wave * 64) * 8], Amb + (size_t)(r0 + (t >> 2)) * 512 + kb + (t & 3) * 8);
        *(bf16x8*)&Bs[srow * 32 + sq4] = pack8(w0, w1);
        __syncthreads();
        if (kb + 32 < 512) {
            const float* p = wop + kb + 32;
            w0 = *(const float4*)p; w1 = *(const float4*)(p + 4);
        }
        bf16x8 af = *(const bf16x8*)&As[(wave * 16 + cl) * 32 + rg4 * 8];
        #pragma unroll
        for (int cj = 0; cj < 4; ++cj) {
            bf16x8 bg = *(const bf16x8*)&Bs[(cj * 16 + cl) * 32 + rg4 * 8];
            acc[cj] = __builtin_amdgcn_mfma_f32_16x16x32_bf16(af, bg, acc[cj], 0, 0, 0);
        }
    }

    float bov[4];
    #pragma unroll
    for (int cj = 0; cj < 4; ++cj) bov[cj] = bo[j0 + cj * 16 + cl];
    #pragma unroll
    for (int rr = 0; rr < 4; ++rr) {
        const int row_g = r0 + wave * 16 + rg4 * 4 + rr;
        #pragma unroll
        for (int cj = 0; cj < 4; ++cj)
            out[(size_t)row_g * EDIM + j0 + cj * 16 + cl] = acc[cj][rr] + bov[cj];
    }
}

extern "C" void kernel_launch(void* const* d_in, const int* in_sizes, int n_in,
                              void* d_out, int out_size, void* d_ws, size_t ws_size,
                              hipStream_t stream) {
    const float* X  = (const float*)d_in[0];
    const float* Wq = (const float*)d_in[1]; const float* bq = (const float*)d_in[2];
    const float* Wk = (const float*)d_in[3]; const float* bk = (const float*)d_in[4];
    const float* Wv = (const float*)d_in[5]; const float* bv = (const float*)d_in[6];
    const float* Wo = (const float*)d_in[7]; const float* bo = (const float*)d_in[8];
    float* out = (float*)d_out;
    char* base = (char*)d_ws;
    u16*   qf  = (u16*)(base + 0);           // 4 MB
    u16*   kf  = (u16*)(base + 4194304);     // 4 MB
    u16*   vf  = (u16*)(base + 8388608);     // 2 MB
    u16*   KVc = (u16*)(base + 10485760);    // 8 MB (16*32*8192 bf16)
    float* K1c = (float*)(base + 18874368);  // 256 KB
    u16*   Spt = (u16*)(base + 19136512);    // 8 MB
    float* K1p = (float*)(base + 27525120);  // 256 KB
    u16*   Amb = (u16*)(base + 27787264);    // 2 MB (total ~28.5 MB)

    hipLaunchKernelGGL(qkvchunk_kernel, dim3(256), dim3(256), 0, stream,
                       X, Wq, bq, Wk, bk, Wv, bv, qf, kf, vf, KVc, K1c);
    hipLaunchKernelGGL(prefix_kernel, dim3(512), dim3(256), 0, stream, KVc, K1c, Spt, K1p);
    hipLaunchKernelGGL(attn_kernel, dim3(512), dim3(256), 0, stream,
                       qf, kf, vf, Spt, K1p, Amb);
    hipLaunchKernelGGL(out_mfma_kernel, dim3(32, 8), dim3(256), 0, stream,
                       Amb, Wo, bo, out);
}

// Round 7
// 109.534 us; speedup vs baseline: 1.0402x; 1.0402x over previous
//
#include <hip/hip_runtime.h>
#include <math.h>

#define LSEQ 1024
#define EDIM 512
#define HD 64
#define CCH 64        // chunk length
#define NCH 16        // chunks per head
#define DFEAT 128

typedef unsigned short u16;
typedef short bf16x8 __attribute__((ext_vector_type(8)));
typedef float f32x4 __attribute__((ext_vector_type(4)));

__device__ __forceinline__ u16 f2bf(float f) {
    unsigned u = __float_as_uint(f);
    unsigned r = (u + 0x7fffu + ((u >> 16) & 1u)) >> 16;
    return (u16)r;
}
__device__ __forceinline__ float bf2f(u16 x) {
    return __uint_as_float((unsigned)x << 16);
}
__device__ __forceinline__ void async16(void* lds, const void* g) {
    __builtin_amdgcn_global_load_lds(
        (const __attribute__((address_space(1))) unsigned int*)g,
        (__attribute__((address_space(3))) unsigned int*)lds, 16, 0, 0);
}

// ---------------- cast fp32 -> bf16 for X and the 4 weight matrices
__global__ __launch_bounds__(256) void cast_kernel(
    const float* __restrict__ X,  const float* __restrict__ Wq,
    const float* __restrict__ Wk, const float* __restrict__ Wv,
    const float* __restrict__ Wo, u16* __restrict__ Xb, u16* __restrict__ Wb)
{
    int i = blockIdx.x * 256 + threadIdx.x;   // one float4 group per thread
    const float* src; u16* dst; int off;
    if (i < 262144)      { src = X;  dst = Xb;          off = i; }
    else if (i < 327680) { src = Wq; dst = Wb;          off = i - 262144; }
    else if (i < 393216) { src = Wk; dst = Wb + 262144; off = i - 327680; }
    else if (i < 458752) { src = Wv; dst = Wb + 524288; off = i - 393216; }
    else                 { src = Wo; dst = Wb + 786432; off = i - 458752; }
    float4 v = *(const float4*)&src[(size_t)off * 4];
    ushort4 o; o.x = f2bf(v.x); o.y = f2bf(v.y); o.z = f2bf(v.z); o.w = f2bf(v.w);
    *(ushort4*)&dst[(size_t)off * 4] = o;
}

// ---------------- QKV projection via bf16 MFMA (128x64 tiles, 384 blocks)
__global__ __launch_bounds__(256) void qkv_mfma_kernel(
    const u16* __restrict__ Xb, const u16* __restrict__ Wb,
    const float* __restrict__ bq, const float* __restrict__ bk, const float* __restrict__ bv,
    u16* __restrict__ qf, u16* __restrict__ kf, u16* __restrict__ vf)
{
    const int z = blockIdx.z;
    const u16* __restrict__ W = Wb + (size_t)z * 262144;
    const float* __restrict__ bias = (z == 0) ? bq : (z == 1) ? bk : bv;
    const int r0 = blockIdx.x * 128;
    const int j0 = blockIdx.y * 64;
    __shared__ u16 As[128 * 32];
    __shared__ u16 Bs[64 * 32];
    const int t = threadIdx.x;
    const int wave = t >> 6, lane = t & 63;
    const int cl = lane & 15, rg4 = lane >> 4;
    f32x4 acc[2][4];
    #pragma unroll
    for (int ri = 0; ri < 2; ++ri)
        #pragma unroll
        for (int cj = 0; cj < 4; ++cj) acc[ri][cj] = (f32x4){0.f, 0.f, 0.f, 0.f};

    for (int kb = 0; kb < 512; kb += 32) {
        #pragma unroll
        for (int i = 0; i < 2; ++i) {
            int chunk = i * 256 + t;
            int row = chunk >> 2, kg = chunk & 3;
            async16(&As[(i * 256 + wave * 64) * 8], Xb + (size_t)(r0 + row) * 512 + kb + kg * 8);
        }
        {
            int row = t >> 2, kg = t & 3;
            async16(&Bs[(wave * 64) * 8], W + (size_t)(j0 + row) * 512 + kb + kg * 8);
        }
        __syncthreads();
        bf16x8 af[2], bg[4];
        #pragma unroll
        for (int ri = 0; ri < 2; ++ri)
            af[ri] = *(const bf16x8*)&As[(wave * 32 + ri * 16 + cl) * 32 + rg4 * 8];
        #pragma unroll
        for (int cj = 0; cj < 4; ++cj)
            bg[cj] = *(const bf16x8*)&Bs[(cj * 16 + cl) * 32 + rg4 * 8];
        #pragma unroll
        for (int ri = 0; ri < 2; ++ri)
            #pragma unroll
            for (int cj = 0; cj < 4; ++cj)
                acc[ri][cj] = __builtin_amdgcn_mfma_f32_16x16x32_bf16(af[ri], bg[cj], acc[ri][cj], 0, 0, 0);
        __syncthreads();
    }

    float biasv[4];
    #pragma unroll
    for (int cj = 0; cj < 4; ++cj) biasv[cj] = bias[j0 + cj * 16 + cl];
    const int h = j0 >> 6;
    #pragma unroll
    for (int ri = 0; ri < 2; ++ri) {
        #pragma unroll
        for (int rr = 0; rr < 4; ++rr) {
            const int row_g = r0 + wave * 32 + ri * 16 + rg4 * 4 + rr;
            const int l = row_g >> 1, bb = row_g & 1;
            if (z < 2) {
                float ang = 1.5707963267948966f * (float)(l + 1) * (1.0f / 1024.0f);
                float sv, cv;
                sincosf(ang, &sv, &cv);
                u16* __restrict__ dst = (z == 0) ? qf : kf;
                size_t base = (size_t)((bb * 8 + h) * LSEQ + l) * DFEAT;
                #pragma unroll
                for (int cj = 0; cj < 4; ++cj) {
                    const int d = cj * 16 + cl;
                    float y = fmaxf(acc[ri][cj][rr] + biasv[cj], 0.f);
                    dst[base + d]      = f2bf(y * sv);
                    dst[base + d + 64] = f2bf(y * cv);
                }
            } else {
                size_t base = (size_t)((bb * 8 + h) * LSEQ + l) * HD;
                #pragma unroll
                for (int cj = 0; cj < 4; ++cj) {
                    const int d = cj * 16 + cl;
                    vf[base + d] = f2bf(acc[ri][cj][rr] + biasv[cj]);
                }
            }
        }
    }
}

// ---------------- per-chunk KV sums via MFMA -> bf16 KVc ; fp32 K1 sums (C=64)
__global__ __launch_bounds__(256) void chunk_sum_kernel(
    const u16* __restrict__ kf, const u16* __restrict__ vf,
    u16* __restrict__ KVc, float* __restrict__ K1c)
{
    const int n = blockIdx.x >> 4;
    const int c = blockIdx.x & 15;
    __shared__ u16 Ks[64 * 128];   // l-major K chunk (async dest, unpadded)
    __shared__ u16 KT[128 * 68];   // transposed K, padded rows
    __shared__ u16 Vs[64 * 64];    // l-major V chunk (async dest)
    __shared__ u16 VT[64 * 68];    // transposed V, padded rows
    const int t = threadIdx.x;
    const int wave = t >> 6, lane = t & 63;
    const int cl = lane & 15, rg4 = lane >> 4;
    const u16* kbase = kf + (size_t)(n * LSEQ + c * CCH) * DFEAT;
    const u16* vbase = vf + (size_t)(n * LSEQ + c * CCH) * HD;
    #pragma unroll
    for (int i = 0; i < 4; ++i)
        async16(&Ks[(i * 256 + wave * 64) * 8], kbase + (size_t)(i * 256 + t) * 8);
    #pragma unroll
    for (int i = 0; i < 2; ++i)
        async16(&Vs[(i * 256 + wave * 64) * 8], vbase + (size_t)(i * 256 + t) * 8);
    __syncthreads();
    {   // V transpose: thread -> (m = t&63, l0 = (t>>6)*16)
        int m = t & 63, l0 = (t >> 6) * 16;
        #pragma unroll
        for (int half = 0; half < 2; ++half) {
            u16 tmp[8];
            #pragma unroll
            for (int j = 0; j < 8; ++j) tmp[j] = Vs[(l0 + half * 8 + j) * 64 + m];
            *(bf16x8*)&VT[m * 68 + l0 + half * 8] = *(bf16x8*)tmp;
        }
    }
    {   // K transpose: thread -> (d = t&127, l0 = (t>>7)*32)
        int d = t & 127, l0 = (t >> 7) * 32;
        #pragma unroll
        for (int q = 0; q < 4; ++q) {
            u16 tmp[8];
            #pragma unroll
            for (int j = 0; j < 8; ++j) tmp[j] = Ks[(l0 + q * 8 + j) * 128 + d];
            *(bf16x8*)&KT[d * 68 + l0 + q * 8] = *(bf16x8*)tmp;
        }
    }
    __syncthreads();
    // KVc[m][d] = sum_l V[l][m] * K[l][d]
    bf16x8 af[2];
    #pragma unroll
    for (int ks = 0; ks < 2; ++ks)
        af[ks] = *(const bf16x8*)&VT[(wave * 16 + cl) * 68 + ks * 32 + rg4 * 8];
    u16* kvout = KVc + (size_t)(n * NCH + c) * (HD * DFEAT);
    #pragma unroll
    for (int dt = 0; dt < 8; ++dt) {
        f32x4 acc = (f32x4){0.f, 0.f, 0.f, 0.f};
        #pragma unroll
        for (int ks = 0; ks < 2; ++ks) {
            bf16x8 bfr = *(const bf16x8*)&KT[(dt * 16 + cl) * 68 + ks * 32 + rg4 * 8];
            acc = __builtin_amdgcn_mfma_f32_16x16x32_bf16(af[ks], bfr, acc, 0, 0, 0);
        }
        #pragma unroll
        for (int r = 0; r < 4; ++r)
            kvout[(size_t)(wave * 16 + rg4 * 4 + r) * 128 + dt * 16 + cl] = f2bf(acc[r]);
    }
    if (t < 128) {
        float s = 0.f;
        #pragma unroll
        for (int g = 0; g < 8; ++g) {
            bf16x8 kv = *(const bf16x8*)&KT[t * 68 + g * 8];
            #pragma unroll
            for (int j = 0; j < 8; ++j) s += bf2f(((u16*)&kv)[j]);
        }
        K1c[(size_t)(n * NCH + c) * DFEAT + t] = s;
    }
}

// ---------------- exclusive prefix over chunks (bf16 KVc -> bf16 Spt; K1 -> fp32)
__global__ __launch_bounds__(256) void prefix_kernel(
    const u16* __restrict__ KVc, const float* __restrict__ K1c,
    u16* __restrict__ Spt, float* __restrict__ K1p)
{
    const int b = blockIdx.x, t = threadIdx.x;
    const int n = b >> 5;
    const int e = (b & 31) * 256 + t;   // 0..8191 (m*128+d)
    const u16* src = KVc + (size_t)n * NCH * 8192 + e;
    u16* dst = Spt + (size_t)n * NCH * 8192 + e;
    float v[NCH];
    #pragma unroll
    for (int cc = 0; cc < NCH; ++cc) v[cc] = bf2f(src[(size_t)cc * 8192]);
    float run = 0.f;
    #pragma unroll
    for (int cc = 0; cc < NCH; ++cc) { dst[(size_t)cc * 8192] = f2bf(run); run += v[cc]; }
    if (b < 8) {
        const int idx = b * 256 + t;  // 0..2047
        const int nn = idx >> 7, d = idx & 127;
        const float* s2 = K1c + (size_t)nn * NCH * DFEAT + d;
        float* d2 = K1p + (size_t)nn * NCH * DFEAT + d;
        float v2[NCH];
        #pragma unroll
        for (int cc = 0; cc < NCH; ++cc) v2[cc] = s2[cc * DFEAT];
        float run2 = 0.f;
        #pragma unroll
        for (int cc = 0; cc < NCH; ++cc) { d2[cc * DFEAT] = run2; run2 += v2[cc]; }
    }
}

// ---------------- intra-chunk attention via MFMA + prefix terms + normalize (C=64)
__global__ __launch_bounds__(256) void attn_kernel(
    const u16* __restrict__ qf, const u16* __restrict__ kf, const u16* __restrict__ vf,
    const u16* __restrict__ Spt, const float* __restrict__ K1p,
    u16* __restrict__ Amb)
{
    const int n = blockIdx.x >> 4;
    const int c = blockIdx.x & 15;
    __shared__ u16 Qs[64 * 136];   // padded rows
    __shared__ u16 Ks[64 * 136];
    __shared__ u16 VT[64 * 68];    // [m][l], padded
    __shared__ u16 Am[64 * 68];    // masked A, bf16, l-major, padded
    __shared__ float K1s[128];
    __shared__ float dsum[64];
    __shared__ float qk1[64];
    const int t = threadIdx.x;
    const int wave = t >> 6, lane = t & 63;
    const int cl = lane & 15, rg4 = lane >> 4;

    const u16* qbase = qf + (size_t)(n * LSEQ + c * CCH) * DFEAT;
    const u16* kbase = kf + (size_t)(n * LSEQ + c * CCH) * DFEAT;
    const u16* vbase = vf + (size_t)(n * LSEQ + c * CCH) * HD;
    const u16* spbase = Spt + (size_t)(n * NCH + c) * 8192;

    // prefetch S_prev B-frags straight from global (16B per lane):
    // B[k=d][nv=m]: spf[nj][ks] <- Spt[m = nj*16+cl][d = ks*32 + rg4*8 ..+7]
    bf16x8 spf[4][4];
    #pragma unroll
    for (int nj = 0; nj < 4; ++nj)
        #pragma unroll
        for (int ks = 0; ks < 4; ++ks)
            spf[nj][ks] = *(const bf16x8*)&spbase[(nj * 16 + cl) * 128 + ks * 32 + rg4 * 8];

    // stage Q,K into padded LDS
    #pragma unroll
    for (int i = 0; i < 4; ++i) {
        int chunk = i * 256 + t;            // 0..1023
        int row = chunk >> 4, c8 = chunk & 15;
        *(bf16x8*)&Qs[row * 136 + c8 * 8] = *(const bf16x8*)&qbase[row * 128 + c8 * 8];
        *(bf16x8*)&Ks[row * 136 + c8 * 8] = *(const bf16x8*)&kbase[row * 128 + c8 * 8];
    }
    {   // V transpose (coalesced scalar reads), wave w covers l = 16w..16w+15
        #pragma unroll
        for (int half = 0; half < 2; ++half) {
            u16 tmp[8];
            #pragma unroll
            for (int j = 0; j < 8; ++j) tmp[j] = vbase[(wave * 16 + half * 8 + j) * HD + lane];
            *(bf16x8*)&VT[lane * 68 + wave * 16 + half * 8] = *(bf16x8*)tmp;
        }
    }
    if (t < 128) K1s[t] = K1p[(size_t)(n * NCH + c) * DFEAT + t];
    __syncthreads();

    // QK^T: wave owns row-tile mi=wave, all 4 col-tiles
    f32x4 a_acc[4];
    #pragma unroll
    for (int nj = 0; nj < 4; ++nj) a_acc[nj] = (f32x4){0.f, 0.f, 0.f, 0.f};
    #pragma unroll
    for (int ks = 0; ks < 4; ++ks) {
        bf16x8 aq = *(const bf16x8*)&Qs[(wave * 16 + cl) * 136 + ks * 32 + rg4 * 8];
        #pragma unroll
        for (int nj = 0; nj < 4; ++nj) {
            bf16x8 bk = *(const bf16x8*)&Ks[(nj * 16 + cl) * 136 + ks * 32 + rg4 * 8];
            a_acc[nj] = __builtin_amdgcn_mfma_f32_16x16x32_bf16(aq, bk, a_acc[nj], 0, 0, 0);
        }
    }
    // mask, wave-local fp32 rowsum, write bf16 A
    #pragma unroll
    for (int r = 0; r < 4; ++r) {
        int l_loc = wave * 16 + rg4 * 4 + r;
        float rs = 0.f;
        #pragma unroll
        for (int nj = 0; nj < 4; ++nj) {
            int lp = nj * 16 + cl;
            float v = (lp <= l_loc) ? a_acc[nj][r] : 0.f;
            Am[l_loc * 68 + lp] = f2bf(v);
            rs += v;
        }
        rs += __shfl_xor(rs, 1); rs += __shfl_xor(rs, 2);
        rs += __shfl_xor(rs, 4); rs += __shfl_xor(rs, 8);
        if (cl == 0) dsum[l_loc] = rs;
    }
    {   // q . K1_prev: 4 lanes per row, 32 d each
        int row = wave * 16 + (lane >> 2), seg = lane & 3;
        float s = 0.f;
        #pragma unroll
        for (int j = 0; j < 32; ++j) {
            int d = seg * 32 + j;
            s += bf2f(Qs[row * 136 + d]) * K1s[d];
        }
        s += __shfl_xor(s, 1); s += __shfl_xor(s, 2);
        if (seg == 0) qk1[row] = s;
    }
    __syncthreads();

    // C = Q @ S_prev + A_masked @ V  (wave: row-tile mi=wave, 4 m_v tiles)
    f32x4 oacc[4];
    #pragma unroll
    for (int nj = 0; nj < 4; ++nj) oacc[nj] = (f32x4){0.f, 0.f, 0.f, 0.f};
    #pragma unroll
    for (int ks = 0; ks < 4; ++ks) {
        bf16x8 aq = *(const bf16x8*)&Qs[(wave * 16 + cl) * 136 + ks * 32 + rg4 * 8];
        #pragma unroll
        for (int nj = 0; nj < 4; ++nj)
            oacc[nj] = __builtin_amdgcn_mfma_f32_16x16x32_bf16(aq, spf[nj][ks], oacc[nj], 0, 0, 0);
    }
    #pragma unroll
    for (int ks2 = 0; ks2 < 2; ++ks2) {
        bf16x8 aa = *(const bf16x8*)&Am[(wave * 16 + cl) * 68 + ks2 * 32 + rg4 * 8];
        #pragma unroll
        for (int nj = 0; nj < 4; ++nj) {
            bf16x8 bv = *(const bf16x8*)&VT[(nj * 16 + cl) * 68 + ks2 * 32 + rg4 * 8];
            oacc[nj] = __builtin_amdgcn_mfma_f32_16x16x32_bf16(aa, bv, oacc[nj], 0, 0, 0);
        }
    }
    // normalize + scatter to Amb
    const int bb = n >> 3, h = n & 7;
    #pragma unroll
    for (int r = 0; r < 4; ++r) {
        int l_loc = wave * 16 + rg4 * 4 + r;
        float den = fmaxf(dsum[l_loc] + qk1[l_loc], 1e-6f);
        float inv = 1.0f / den;
        int rrow = (c * CCH + l_loc) * 2 + bb;
        #pragma unroll
        for (int nj = 0; nj < 4; ++nj) {
            int m = nj * 16 + cl;
            Amb[(size_t)rrow * EDIM + h * 64 + m] = f2bf(oacc[nj][r] * inv);
        }
    }
}

// ---------------- output projection via bf16 MFMA (64x64 tiles, 256 blocks)
__global__ __launch_bounds__(256) void out_mfma_kernel(
    const u16* __restrict__ Amb, const u16* __restrict__ Wob,
    const float* __restrict__ bo, float* __restrict__ out)
{
    const int r0 = blockIdx.x * 64;
    const int j0 = blockIdx.y * 64;
    __shared__ u16 As[64 * 32];
    __shared__ u16 Bs[64 * 32];
    const int t = threadIdx.x;
    const int wave = t >> 6, lane = t & 63;
    const int cl = lane & 15, rg4 = lane >> 4;
    f32x4 acc[4];
    #pragma unroll
    for (int cj = 0; cj < 4; ++cj) acc[cj] = (f32x4){0.f, 0.f, 0.f, 0.f};

    for (int kb = 0; kb < 512; kb += 32) {
        {
            int row = t >> 2, kg = t & 3;
            async16(&As[(wave * 64) * 8], Amb + (size_t)(r0 + row) * 512 + kb + kg * 8);
            async16(&Bs[(wave * 64) * 8], Wob + (size_t)(j0 + row) * 512 + kb + kg * 8);
        }
        __syncthreads();
        bf16x8 af = *(const bf16x8*)&As[(wave * 16 + cl) * 32 + rg4 * 8];
        bf16x8 bg[4];
        #pragma unroll
        for (int cj = 0; cj < 4; ++cj)
            bg[cj] = *(const bf16x8*)&Bs[(cj * 16 + cl) * 32 + rg4 * 8];
        #pragma unroll
        for (int cj = 0; cj < 4; ++cj)
            acc[cj] = __builtin_amdgcn_mfma_f32_16x16x32_bf16(af, bg[cj], acc[cj], 0, 0, 0);
        __syncthreads();
    }

    float bov[4];
    #pragma unroll
    for (int cj = 0; cj < 4; ++cj) bov[cj] = bo[j0 + cj * 16 + cl];
    #pragma unroll
    for (int rr = 0; rr < 4; ++rr) {
        const int row_g = r0 + wave * 16 + rg4 * 4 + rr;
        #pragma unroll
        for (int cj = 0; cj < 4; ++cj)
            out[(size_t)row_g * EDIM + j0 + cj * 16 + cl] = acc[cj][rr] + bov[cj];
    }
}

extern "C" void kernel_launch(void* const* d_in, const int* in_sizes, int n_in,
                              void* d_out, int out_size, void* d_ws, size_t ws_size,
                              hipStream_t stream) {
    const float* X  = (const float*)d_in[0];
    const float* Wq = (const float*)d_in[1]; const float* bq = (const float*)d_in[2];
    const float* Wk = (const float*)d_in[3]; const float* bk = (const float*)d_in[4];
    const float* Wv = (const float*)d_in[5]; const float* bv = (const float*)d_in[6];
    const float* Wo = (const float*)d_in[7]; const float* bo = (const float*)d_in[8];
    float* out = (float*)d_out;
    char* base = (char*)d_ws;
    u16*   qf  = (u16*)(base + 0);           // 4 MB
    u16*   kf  = (u16*)(base + 4194304);     // 4 MB
    u16*   vf  = (u16*)(base + 8388608);     // 2 MB
    u16*   KVc = (u16*)(base + 10485760);    // 16*16*8192 bf16 = 4 MB
    float* K1c = (float*)(base + 14680064);  // 128 KB
    u16*   Spt = (u16*)(base + 14811136);    // 4 MB
    float* K1p = (float*)(base + 19005440);  // 128 KB
    u16*   Amb = (u16*)(base + 19136512);    // 2 MB
    u16*   Xb  = (u16*)(base + 21233664);    // 2 MB
    u16*   Wb  = (u16*)(base + 23330816);    // 4 MB (total ~27.5 MB)

    hipLaunchKernelGGL(cast_kernel, dim3(2048), dim3(256), 0, stream,
                       X, Wq, Wk, Wv, Wo, Xb, Wb);
    hipLaunchKernelGGL(qkv_mfma_kernel, dim3(16, 8, 3), dim3(256), 0, stream,
                       Xb, Wb, bq, bk, bv, qf, kf, vf);
    hipLaunchKernelGGL(chunk_sum_kernel, dim3(256), dim3(256), 0, stream, kf, vf, KVc, K1c);
    hipLaunchKernelGGL(prefix_kernel, dim3(512), dim3(256), 0, stream, KVc, K1c, Spt, K1p);
    hipLaunchKernelGGL(attn_kernel, dim3(256), dim3(256), 0, stream,
                       qf, kf, vf, Spt, K1p, Amb);
    hipLaunchKernelGGL(out_mfma_kernel, dim3(32, 8), dim3(256), 0, stream,
                       Amb, Wb + 786432, bo, out);
}